// Round 1
// baseline (4894.836 us; speedup 1.0000x reference)
//
#include <hip/hip_runtime.h>
#include <hip/hip_bf16.h>
#include <stdint.h>

typedef __bf16 bf16_t;
typedef __bf16 bf16x8 __attribute__((ext_vector_type(8)));
typedef __bf16 bf16x4 __attribute__((ext_vector_type(4)));
typedef float  f32x4  __attribute__((ext_vector_type(4)));

#define SEQ   512
#define BATCH 32
#define HID   1024
#define FFD   4096
#define NROW  (SEQ*BATCH)          /* 16384 rows, layout [s][b][feat] */
#define NTOT  ((long)NROW*HID)     /* 16,777,216 */

typedef __attribute__((address_space(3))) uint32_t lds_u32;
typedef __attribute__((address_space(1))) const uint32_t glb_u32;

__device__ __forceinline__ void gload_lds16(const void* g, void* l) {
  // CK-pattern addrspace reinterpret; LDS dest is wave-uniform base + lane*16
  glb_u32* gp = reinterpret_cast<glb_u32*>(reinterpret_cast<uintptr_t>(g));
  lds_u32* lp = reinterpret_cast<lds_u32*>(reinterpret_cast<uintptr_t>(l));
  __builtin_amdgcn_global_load_lds(gp, lp, 16, 0, 0);
}

// ---------------- embedding: h = emb[x]*32 + pos[s]; also bf16 copy --------
__global__ __launch_bounds__(256) void embed_k(const int* __restrict__ x,
    const float* __restrict__ emb, const float* __restrict__ pos,
    float* __restrict__ h, bf16_t* __restrict__ hb)
{
  const long row = blockIdx.x;           // row = s*32 + b
  const int  s   = (int)(row >> 5);
  const long idx = x[row];
  const int  t   = threadIdx.x;
  float4 e  = ((const float4*)(emb + idx*HID))[t];
  float4 pv = ((const float4*)(pos + (long)s*HID))[t];
  float4 o  = {e.x*32.f+pv.x, e.y*32.f+pv.y, e.z*32.f+pv.z, e.w*32.f+pv.w};
  ((float4*)(h + row*HID))[t] = o;
  bf16x4 ob = {(bf16_t)o.x, (bf16_t)o.y, (bf16_t)o.z, (bf16_t)o.w};
  *(bf16x4*)(hb + row*HID + (long)t*4) = ob;
}

// ------------- weight convert + transpose: wT[n][k] = bf16(w[k][n]) --------
__global__ __launch_bounds__(256) void wcvt(const float* __restrict__ w,
    bf16_t* __restrict__ wT, int K, int N)
{
  __shared__ float tile[32][33];
  const int tx = threadIdx.x & 31, ty = threadIdx.x >> 5;   // ty 0..7
  const int ntx = N >> 5;
  const int n0 = (blockIdx.x % ntx) << 5;
  const int k0 = (blockIdx.x / ntx) << 5;
#pragma unroll
  for (int i = 0; i < 4; ++i)
    tile[ty + i*8][tx] = w[(long)(k0 + ty + i*8)*N + n0 + tx];
  __syncthreads();
#pragma unroll
  for (int i = 0; i < 4; ++i)
    wT[(long)(n0 + ty + i*8)*K + k0 + tx] = (bf16_t)tile[tx][ty + i*8];
}

// ---------------- bf16 MFMA GEMM, 128x128 tile, BK=64, 4 waves -------------
// C[M,N] = A[M,K] * Bt[N,K]^T   (+bias)  epilogues:
// MODE 0: outB = bf16(acc+bias)    MODE 1: outB = bf16(relu(acc+bias))
// MODE 2: outF = acc + bias + res  (res/outF may be the same buffer)
template<int MODE>
__global__ __launch_bounds__(256)
void gemm128(const bf16_t* __restrict__ A, const bf16_t* __restrict__ Bt,
             const float* __restrict__ bias, const float* __restrict__ res,
             float* __restrict__ outF, bf16_t* __restrict__ outB,
             int M, int N, int K)
{
  __shared__ bf16_t As[128*64];
  __shared__ bf16_t Bs[128*64];
  const int tid = threadIdx.x;
  const int w = tid >> 6, l = tid & 63;
  const int nbn = N >> 7;
  const long bm = blockIdx.x / nbn, bn = blockIdx.x % nbn;
  const long rA0 = bm << 7, rB0 = bn << 7;

  f32x4 acc[4][4];
#pragma unroll
  for (int m = 0; m < 4; ++m)
#pragma unroll
    for (int n = 0; n < 4; ++n) acc[m][n] = (f32x4){0.f, 0.f, 0.f, 0.f};

  const int sr = l >> 3;             // staging row within 8-row chunk
  const int sp = l & 7;              // physical 16B slot
  const int cs = (sp ^ sr) * 8;      // pre-swizzled source col (elems)
  const int wm = (w >> 1) << 6, wn = (w & 1) << 6;
  const int fr = l & 15;             // fragment row(A)/col(B,D)
  const int fk = (l >> 4) << 3;      // fragment k offset (elems)

  for (int k0 = 0; k0 < K; k0 += 64) {
    __syncthreads();
#pragma unroll
    for (int c = 0; c < 4; ++c) {
      const int rt = w*32 + c*8;     // wave-uniform LDS row base
      const bf16_t* ga = A  + (rA0 + rt + sr)*K + k0 + cs;
      const bf16_t* gb = Bt + (rB0 + rt + sr)*K + k0 + cs;
      gload_lds16(ga, &As[rt*64]);
      gload_lds16(gb, &Bs[rt*64]);
    }
    asm volatile("s_waitcnt vmcnt(0)" ::: "memory");
    __syncthreads();
#pragma unroll
    for (int kk = 0; kk < 2; ++kk) {
      bf16x8 af[4], bfr[4];
#pragma unroll
      for (int m = 0; m < 4; ++m) {
        const int r  = wm + m*16 + fr;
        const int cb = ((kk*32 + fk) << 1) ^ ((r & 7) << 4);
        af[m] = *(const bf16x8*)((const char*)As + r*128 + cb);
      }
#pragma unroll
      for (int n = 0; n < 4; ++n) {
        const int r  = wn + n*16 + fr;
        const int cb = ((kk*32 + fk) << 1) ^ ((r & 7) << 4);
        bfr[n] = *(const bf16x8*)((const char*)Bs + r*128 + cb);
      }
#pragma unroll
      for (int m = 0; m < 4; ++m)
#pragma unroll
        for (int n = 0; n < 4; ++n)
          acc[m][n] = __builtin_amdgcn_mfma_f32_16x16x32_bf16(af[m], bfr[n], acc[m][n], 0, 0, 0);
    }
  }
  const int er = (l >> 4) << 2;      // D row group
#pragma unroll
  for (int n = 0; n < 4; ++n) {
    const long col = rB0 + wn + n*16 + fr;
    const float bv = bias[col];
#pragma unroll
    for (int m = 0; m < 4; ++m) {
#pragma unroll
      for (int j = 0; j < 4; ++j) {
        const long row = rA0 + wm + m*16 + er + j;
        const long off = row*(long)N + col;
        const float v = acc[m][n][j] + bv;
        if (MODE == 0)      outB[off] = (bf16_t)v;
        else if (MODE == 1) outB[off] = (bf16_t)fmaxf(v, 0.f);
        else                outF[off] = v + res[off];
      }
    }
  }
}

// ---------------- attention: one block per (b, head) -----------------------
// in_row(t)  = t*256 + head*32 + b   (rows of q/k/v participating)
// out_row(t) = t*256 + b*8 + head    (scrambled reshape collapses to this)
__global__ __launch_bounds__(256) void attn_k(
    const bf16_t* __restrict__ qb, const bf16_t* __restrict__ kb,
    const bf16_t* __restrict__ vb, bf16_t* __restrict__ ob)
{
  __shared__ __align__(16) char smem[64*128*2*2 + 64*64*4 + 64*4];
  bf16_t* Qc = (bf16_t*)smem;                  // 16 KB, xor-swizzled slots
  bf16_t* Kc = (bf16_t*)(smem + 16384);        // 16 KB, xor-swizzled slots
  bf16_t* Vc = (bf16_t*)smem;                  // aliases Qc (phase-disjoint)
  float*  E    = (float*)(smem + 32768);       // 16 KB  E[s][ti] = p values
  float*  Rinv = (float*)(smem + 49152);

  const int tid  = threadIdx.x;
  const int head = blockIdx.x & 7, b = blockIdx.x >> 3;
  const long rbase = (long)head*32 + b;

  const int ti = tid >> 2, g = tid & 3;        // energy owner mapping
  const int lr  = tid >> 2;                    // staging row 0..63
  const int lp0 = (tid & 3) * 4;               // staging first slot

  float eacc[16];
#pragma unroll
  for (int j = 0; j < 16; ++j) eacc[j] = 0.f;

  for (int kc = 0; kc < HID; kc += 128) {
    __syncthreads();
    const bf16_t* qrow = qb + (lr*256 + rbase)*HID + kc;
    const bf16_t* krow = kb + (lr*256 + rbase)*HID + kc;
#pragma unroll
    for (int i = 0; i < 4; ++i) {
      const int p = lp0 + i;
      const int src = (p ^ (lr & 7)) * 8;
      *(uint4*)&Qc[lr*128 + p*8] = *(const uint4*)&qrow[src];
      *(uint4*)&Kc[lr*128 + p*8] = *(const uint4*)&krow[src];
    }
    __syncthreads();
    for (int e8 = 0; e8 < 16; ++e8) {
      const int qp = e8 ^ (ti & 7);
      bf16x8 qv = *(bf16x8*)&Qc[ti*128 + qp*8];
      float qf[8];
#pragma unroll
      for (int u = 0; u < 8; ++u) qf[u] = (float)qv[u];
#pragma unroll
      for (int j = 0; j < 16; ++j) {
        const int s  = j*4 + g;
        const int kp = e8 ^ (s & 7);
        bf16x8 kv = *(bf16x8*)&Kc[s*128 + kp*8];
        float a = eacc[j];
#pragma unroll
        for (int u = 0; u < 8; ++u) a += qf[u] * (float)kv[u];
        eacc[j] = a;
      }
    }
  }
  // softmax over s for each ti (4 threads per ti; shfl within 4-lane group)
  const float scale = 0.0883883476483184f;     // 1/sqrt(128)
  float mx = -1e30f;
#pragma unroll
  for (int j = 0; j < 16; ++j) { eacc[j] *= scale; mx = fmaxf(mx, eacc[j]); }
  mx = fmaxf(mx, __shfl_xor(mx, 1));
  mx = fmaxf(mx, __shfl_xor(mx, 2));
  float sum = 0.f;
#pragma unroll
  for (int j = 0; j < 16; ++j) {
    const float pj = __expf(eacc[j] - mx);
    E[(j*4 + g)*64 + ti] = pj;
    sum += pj;
  }
  sum += __shfl_xor(sum, 1);
  sum += __shfl_xor(sum, 2);
  if (g == 0) Rinv[ti] = 1.f / sum;
  __syncthreads();

  // PV: lane = output row t, wave = feature quarter
  const int lane = tid & 63, wq_ = tid >> 6;
  const float rv = Rinv[lane];
  const long orow = (long)lane*256 + b*8 + head;
  for (int fc = 0; fc < HID; fc += 128) {
    __syncthreads();
    const bf16_t* vrow = vb + (lr*256 + rbase)*HID + fc;
#pragma unroll
    for (int i = 0; i < 4; ++i) {
      const int p = lp0 + i;
      *(uint4*)&Vc[lr*128 + p*8] = *(const uint4*)&vrow[p*8];
    }
    __syncthreads();
    float vacc[32];
#pragma unroll
    for (int u = 0; u < 32; ++u) vacc[u] = 0.f;
    for (int s = 0; s < 64; ++s) {
      const float pp = E[s*64 + lane];
#pragma unroll
      for (int u = 0; u < 4; ++u) {
        bf16x8 vv = *(bf16x8*)&Vc[s*128 + wq_*32 + u*8];
#pragma unroll
        for (int t8 = 0; t8 < 8; ++t8) vacc[u*8 + t8] += pp * (float)vv[t8];
      }
    }
#pragma unroll
    for (int u = 0; u < 4; ++u) {
      bf16x8 ov;
#pragma unroll
      for (int t8 = 0; t8 < 8; ++t8) ov[t8] = (bf16_t)(vacc[u*8 + t8] * rv);
      *(bf16x8*)&ob[orow*HID + fc + wq_*32 + u*8] = ov;
    }
  }
}

// ---------------- global layer-norm: 2-stage reduce + normalize ------------
__global__ __launch_bounds__(256) void reduce1(const float* __restrict__ t,
                                               float* __restrict__ part, long n4)
{
  float s = 0.f, s2 = 0.f;
  for (long i = (long)blockIdx.x*blockDim.x + threadIdx.x; i < n4;
       i += (long)gridDim.x*blockDim.x) {
    float4 v = ((const float4*)t)[i];
    s  += v.x + v.y + v.z + v.w;
    s2 += v.x*v.x + v.y*v.y + v.z*v.z + v.w*v.w;
  }
  __shared__ float sh[256], sh2[256];
  const int tid = threadIdx.x;
  sh[tid] = s; sh2[tid] = s2; __syncthreads();
  for (int o = 128; o > 0; o >>= 1) {
    if (tid < o) { sh[tid] += sh[tid+o]; sh2[tid] += sh2[tid+o]; }
    __syncthreads();
  }
  if (tid == 0) { part[blockIdx.x] = sh[0]; part[2048 + blockIdx.x] = sh2[0]; }
}

__global__ __launch_bounds__(256) void reduce2(const float* __restrict__ part,
                                               float* __restrict__ stats)
{
  __shared__ double sh[256], sh2[256];
  const int tid = threadIdx.x;
  double s = 0.0, s2 = 0.0;
  for (int i = tid; i < 2048; i += 256) { s += part[i]; s2 += part[2048 + i]; }
  sh[tid] = s; sh2[tid] = s2; __syncthreads();
  for (int o = 128; o > 0; o >>= 1) {
    if (tid < o) { sh[tid] += sh[tid+o]; sh2[tid] += sh2[tid+o]; }
    __syncthreads();
  }
  if (tid == 0) {
    const double n = (double)NTOT;
    const double mean = sh[0] / n;
    const double var  = sh2[0] / n - mean*mean;
    stats[0] = (float)mean;
    stats[1] = (float)(1.0 / sqrt(var + 1e-5));
  }
}

__global__ __launch_bounds__(256) void ln_norm(const float* __restrict__ t,
    const float* __restrict__ stats, float* __restrict__ outF,
    bf16_t* __restrict__ outB, long n4)
{
  const float mean = stats[0], rstd = stats[1];
  for (long i = (long)blockIdx.x*blockDim.x + threadIdx.x; i < n4;
       i += (long)gridDim.x*blockDim.x) {
    float4 v = ((const float4*)t)[i];
    float4 o = {(v.x-mean)*rstd, (v.y-mean)*rstd, (v.z-mean)*rstd, (v.w-mean)*rstd};
    ((float4*)outF)[i] = o;
    bf16x4 ob = {(bf16_t)o.x, (bf16_t)o.y, (bf16_t)o.z, (bf16_t)o.w};
    ((bf16x4*)outB)[i] = ob;
  }
}

// ---------------------------------------------------------------------------
extern "C" void kernel_launch(void* const* d_in, const int* in_sizes, int n_in,
                              void* d_out, int out_size, void* d_ws, size_t ws_size,
                              hipStream_t stream)
{
  const int*   x    = (const int*)  d_in[0];
  const float* emb  = (const float*)d_in[1];
  const float* pos  = (const float*)d_in[2];
  const float* wq_a = (const float*)d_in[3];
  const float* bq_a = (const float*)d_in[4];
  const float* wk_a = (const float*)d_in[5];
  const float* bk_a = (const float*)d_in[6];
  const float* wv_a = (const float*)d_in[7];
  const float* bv_a = (const float*)d_in[8];
  const float* wo_a = (const float*)d_in[9];
  const float* bo_a = (const float*)d_in[10];
  const float* w1_a = (const float*)d_in[11];
  const float* b1_a = (const float*)d_in[12];
  const float* w2_a = (const float*)d_in[13];
  const float* b2_a = (const float*)d_in[14];

  char* p = (char*)d_ws;
  auto take = [&](size_t n) { char* r = p; p += (n + 255) & ~(size_t)255; return r; };
  float*  h    = (float*) take(NTOT*4);                 // 64 MB  (also a+x / mid+f in place)
  bf16_t* hb   = (bf16_t*)take(NTOT*2);                 // 32 MB  bf16 of current hidden
  bf16_t* U    = (bf16_t*)take((size_t)NROW*FFD*2);     // 128 MB union
  bf16_t* qb   = U;
  bf16_t* kb   = U + NTOT;
  bf16_t* vbuf = U + 2*NTOT;
  bf16_t* attb = U + 3*NTOT;
  bf16_t* ff1  = U;                                     // overlays q/k/v/att (dead by then)
  bf16_t* wT   = (bf16_t*)take((size_t)FFD*HID*2);      // 8 MB weight staging
  float*  part = (float*) take(4096*4);
  float*  stats= (float*) take(256);

  const long n4 = NTOT / 4;
  const int gH  = (NROW/128)*(HID/128);                 // 1024 blocks
  const int gF  = (NROW/128)*(FFD/128);                 // 4096 blocks

  embed_k<<<NROW, 256, 0, stream>>>(x, emb, pos, h, hb);

  for (int i = 0; i < 6; ++i) {
    const float* Wq = wq_a + (size_t)i*HID*HID;  const float* Bq = bq_a + (size_t)i*HID;
    const float* Wk = wk_a + (size_t)i*HID*HID;  const float* Bk = bk_a + (size_t)i*HID;
    const float* Wv = wv_a + (size_t)i*HID*HID;  const float* Bv = bv_a + (size_t)i*HID;
    const float* Wo = wo_a + (size_t)i*HID*HID;  const float* Bo = bo_a + (size_t)i*HID;
    const float* W1 = w1_a + (size_t)i*HID*FFD;  const float* B1 = b1_a + (size_t)i*FFD;
    const float* W2 = w2_a + (size_t)i*FFD*HID;  const float* B2 = b2_a + (size_t)i*HID;

    wcvt<<<(HID/32)*(HID/32), 256, 0, stream>>>(Wq, wT, HID, HID);
    gemm128<0><<<gH, 256, 0, stream>>>(hb, wT, Bq, nullptr, nullptr, qb, NROW, HID, HID);
    wcvt<<<(HID/32)*(HID/32), 256, 0, stream>>>(Wk, wT, HID, HID);
    gemm128<0><<<gH, 256, 0, stream>>>(hb, wT, Bk, nullptr, nullptr, kb, NROW, HID, HID);
    wcvt<<<(HID/32)*(HID/32), 256, 0, stream>>>(Wv, wT, HID, HID);
    gemm128<0><<<gH, 256, 0, stream>>>(hb, wT, Bv, nullptr, nullptr, vbuf, NROW, HID, HID);

    attn_k<<<256, 256, 0, stream>>>(qb, kb, vbuf, attb);

    wcvt<<<(HID/32)*(HID/32), 256, 0, stream>>>(Wo, wT, HID, HID);
    gemm128<2><<<gH, 256, 0, stream>>>(attb, wT, Bo, h, h, nullptr, NROW, HID, HID);

    reduce1<<<2048, 256, 0, stream>>>(h, part, n4);
    reduce2<<<1, 256, 0, stream>>>(part, stats);
    ln_norm<<<2048, 256, 0, stream>>>(h, stats, h, hb, n4);

    wcvt<<<(FFD/32)*(HID/32), 256, 0, stream>>>(W1, wT, HID, FFD);
    gemm128<1><<<gF, 256, 0, stream>>>(hb, wT, B1, nullptr, nullptr, ff1, NROW, FFD, HID);
    wcvt<<<(HID/32)*(FFD/32), 256, 0, stream>>>(W2, wT, FFD, HID);
    gemm128<2><<<gH, 256, 0, stream>>>(ff1, wT, B2, h, h, nullptr, NROW, HID, FFD);

    reduce1<<<2048, 256, 0, stream>>>(h, part, n4);
    reduce2<<<1, 256, 0, stream>>>(part, stats);
    ln_norm<<<2048, 256, 0, stream>>>(h, stats, (i == 5) ? (float*)d_out : h, hb, n4);
  }
}

// Round 2
// 4653.960 us; speedup vs baseline: 1.0518x; 1.0518x over previous
//
#include <hip/hip_runtime.h>
#include <hip/hip_bf16.h>
#include <stdint.h>

typedef __bf16 bf16_t;
typedef __bf16 bf16x8 __attribute__((ext_vector_type(8)));
typedef __bf16 bf16x4 __attribute__((ext_vector_type(4)));
typedef float  f32x4  __attribute__((ext_vector_type(4)));

#define SEQ   512
#define BATCH 32
#define HID   1024
#define FFD   4096
#define NROW  (SEQ*BATCH)          /* 16384 rows, layout [s][b][feat] */
#define NTOT  ((long)NROW*HID)     /* 16,777,216 */

typedef __attribute__((address_space(3))) uint32_t lds_u32;
typedef __attribute__((address_space(1))) const uint32_t glb_u32;

__device__ __forceinline__ void gload_lds16(const void* g, void* l) {
  glb_u32* gp = reinterpret_cast<glb_u32*>(reinterpret_cast<uintptr_t>(g));
  lds_u32* lp = reinterpret_cast<lds_u32*>(reinterpret_cast<uintptr_t>(l));
  __builtin_amdgcn_global_load_lds(gp, lp, 16, 0, 0);
}

#define BAR() asm volatile("s_barrier" ::: "memory")

// ---------------- embedding: h = emb[x]*32 + pos[s]; also bf16 copy --------
__global__ __launch_bounds__(256) void embed_k(const int* __restrict__ x,
    const float* __restrict__ emb, const float* __restrict__ pos,
    float* __restrict__ h, bf16_t* __restrict__ hb)
{
  const long row = blockIdx.x;           // row = s*32 + b
  const int  s   = (int)(row >> 5);
  const long idx = x[row];
  const int  t   = threadIdx.x;
  float4 e  = ((const float4*)(emb + idx*HID))[t];
  float4 pv = ((const float4*)(pos + (long)s*HID))[t];
  float4 o  = {e.x*32.f+pv.x, e.y*32.f+pv.y, e.z*32.f+pv.z, e.w*32.f+pv.w};
  ((float4*)(h + row*HID))[t] = o;
  bf16x4 ob = {(bf16_t)o.x, (bf16_t)o.y, (bf16_t)o.z, (bf16_t)o.w};
  *(bf16x4*)(hb + row*HID + (long)t*4) = ob;
}

// ------------- weight convert + transpose: wT[n][k] = bf16(w[k][n]) --------
__global__ __launch_bounds__(256) void wcvt(const float* __restrict__ w,
    bf16_t* __restrict__ wT, int K, int N)
{
  __shared__ float tile[32][33];
  const int tx = threadIdx.x & 31, ty = threadIdx.x >> 5;   // ty 0..7
  const int ntx = N >> 5;
  const int n0 = (blockIdx.x % ntx) << 5;
  const int k0 = (blockIdx.x / ntx) << 5;
#pragma unroll
  for (int i = 0; i < 4; ++i)
    tile[ty + i*8][tx] = w[(long)(k0 + ty + i*8)*N + n0 + tx];
  __syncthreads();
#pragma unroll
  for (int i = 0; i < 4; ++i)
    wT[(long)(n0 + ty + i*8)*K + k0 + tx] = (bf16_t)tile[tx][ty + i*8];
}

// ============ bf16 MFMA GEMM, 256x256 tile, BK=64, 8 waves, 8-phase ========
// C[M,N] = A[M,K] * Bt[N,K]^T (+bias)
// MODE 0: outB = bf16(acc+bias)   MODE 1: outB = bf16(relu(acc+bias))
// MODE 2: outF = acc + bias + res
// Wave (wm,wn): wm=wid>>2 (2), wn=wid&3 (4). Per-wave out 128x64, rows/cols
// interleaved so each wave touches all 4 (mh,nh) quadrants:
//   row = mh*128 + m'*32 + wm*16 + (0..15),  col = nh*128 + n'*64 + wn*16 + (0..15)
// Phases per K-tile: (0,0),(0,1),(1,0),(1,1). Stages: p0->(t+1,A1),
// p1->(t+1,B1), p2->(t+2,A0), p3->(t+2,B0); one vmcnt(4) per tile boundary.
template<int MODE>
__global__ __launch_bounds__(512, 2)
void gemm256(const bf16_t* __restrict__ A, const bf16_t* __restrict__ Bt,
             const float* bias, const float* res,
             float* __restrict__ outF, bf16_t* __restrict__ outB,
             int M, int N, int K)
{
  __shared__ bf16_t As[2][256*64];
  __shared__ bf16_t Bs[2][256*64];
  const int tid = threadIdx.x;
  const int w = tid >> 6, l = tid & 63;
  const int wm = w >> 2, wn = w & 3;

  // bijective XCD swizzle (m204)
  const int nbn = N >> 8;
  const int nwg = gridDim.x;
  const int q8 = nwg >> 3, r8 = nwg & 7;
  const int xcd = blockIdx.x & 7, bidx = blockIdx.x >> 3;
  const int wg = (xcd < r8 ? xcd*(q8+1) : r8*(q8+1) + (xcd-r8)*q8) + bidx;
  const long bm = wg / nbn, bn = wg % nbn;
  const long rA0 = bm << 8, rB0 = bn << 8;

  // staging geometry: 512 threads cover one 128-row half in 2 loads
  const int srow  = tid >> 3;                       // 0..63
  const int scol  = (((tid & 7) ^ (srow & 7)) << 3);// swizzled src col (elems)
  const int wrow  = w << 3;                         // wave row base (0..56)

  const int fr  = l & 15;
  const int fk2 = ((l >> 4) << 3) * 2;              // frag k byte offset

  f32x4 acc[8][4];
#pragma unroll
  for (int m = 0; m < 8; ++m)
#pragma unroll
    for (int n = 0; n < 4; ++n) acc[m][n] = (f32x4){0.f,0.f,0.f,0.f};

#define STAGE_A(b, h, kt) do { \
    const long kb_ = (long)(kt)*64 + scol; \
    gload_lds16(A + (rA0 + (h)*128 + srow)*(long)K + kb_,      (void*)&As[b][(((h)*128) + wrow)*64]); \
    gload_lds16(A + (rA0 + (h)*128 + 64 + srow)*(long)K + kb_, (void*)&As[b][(((h)*128) + 64 + wrow)*64]); \
  } while (0)
#define STAGE_B(b, h, kt) do { \
    const long kb_ = (long)(kt)*64 + scol; \
    gload_lds16(Bt + (rB0 + (h)*128 + srow)*(long)K + kb_,      (void*)&Bs[b][(((h)*128) + wrow)*64]); \
    gload_lds16(Bt + (rB0 + (h)*128 + 64 + srow)*(long)K + kb_, (void*)&Bs[b][(((h)*128) + 64 + wrow)*64]); \
  } while (0)
#define FRAG(base, r, kk) \
    (*(const bf16x8*)((const char*)(base) + (r)*128 + (((kk)*64 + fk2) ^ (((r) & 7) << 4))))

  const int nk = K >> 6;

  // prologue: tile0 complete + tile1 A0,B0 in flight
  STAGE_A(0, 0, 0); STAGE_B(0, 0, 0); STAGE_A(0, 1, 0); STAGE_B(0, 1, 0);
  STAGE_A(1, 0, 1); STAGE_B(1, 0, 1);
  asm volatile("s_waitcnt vmcnt(4)" ::: "memory");
  BAR();

  for (int t = 0; t < nk; ++t) {
    const int cur = t & 1, nxt = cur ^ 1;
    const bf16_t* Ac = As[cur];
    const bf16_t* Bc = Bs[cur];
    bf16x8 af[4][2], bf0[2][2], bf1[2][2];

    // ---- phase 0: quadrant (0,0); stage (t+1, A1)
    if (t + 1 < nk) STAGE_A(nxt, 1, t + 1);
#pragma unroll
    for (int m = 0; m < 4; ++m)
#pragma unroll
      for (int kk = 0; kk < 2; ++kk)
        af[m][kk] = FRAG(Ac, m*32 + wm*16 + fr, kk);
#pragma unroll
    for (int n = 0; n < 2; ++n)
#pragma unroll
      for (int kk = 0; kk < 2; ++kk)
        bf0[n][kk] = FRAG(Bc, n*64 + wn*16 + fr, kk);
    BAR();
    __builtin_amdgcn_s_setprio(1);
#pragma unroll
    for (int m = 0; m < 4; ++m)
#pragma unroll
      for (int n = 0; n < 2; ++n)
#pragma unroll
        for (int kk = 0; kk < 2; ++kk)
          acc[m][n] = __builtin_amdgcn_mfma_f32_16x16x32_bf16(af[m][kk], bf0[n][kk], acc[m][n], 0, 0, 0);
    __builtin_amdgcn_s_setprio(0);
    BAR();

    // ---- phase 1: quadrant (0,1); stage (t+1, B1)
    if (t + 1 < nk) STAGE_B(nxt, 1, t + 1);
#pragma unroll
    for (int n = 0; n < 2; ++n)
#pragma unroll
      for (int kk = 0; kk < 2; ++kk)
        bf1[n][kk] = FRAG(Bc, 128 + n*64 + wn*16 + fr, kk);
    BAR();
    __builtin_amdgcn_s_setprio(1);
#pragma unroll
    for (int m = 0; m < 4; ++m)
#pragma unroll
      for (int n = 0; n < 2; ++n)
#pragma unroll
        for (int kk = 0; kk < 2; ++kk)
          acc[m][2+n] = __builtin_amdgcn_mfma_f32_16x16x32_bf16(af[m][kk], bf1[n][kk], acc[m][2+n], 0, 0, 0);
    __builtin_amdgcn_s_setprio(0);
    BAR();

    // ---- phase 2: quadrant (1,0); stage (t+2, A0)
    if (t + 2 < nk) STAGE_A(cur, 0, t + 2);
#pragma unroll
    for (int m = 0; m < 4; ++m)
#pragma unroll
      for (int kk = 0; kk < 2; ++kk)
        af[m][kk] = FRAG(Ac, 128 + m*32 + wm*16 + fr, kk);
    BAR();
    __builtin_amdgcn_s_setprio(1);
#pragma unroll
    for (int m = 0; m < 4; ++m)
#pragma unroll
      for (int n = 0; n < 2; ++n)
#pragma unroll
        for (int kk = 0; kk < 2; ++kk)
          acc[4+m][n] = __builtin_amdgcn_mfma_f32_16x16x32_bf16(af[m][kk], bf0[n][kk], acc[4+m][n], 0, 0, 0);
    __builtin_amdgcn_s_setprio(0);
    BAR();

    // ---- phase 3: quadrant (1,1); stage (t+2, B0)
    if (t + 2 < nk) STAGE_B(cur, 0, t + 2);
    BAR();
    __builtin_amdgcn_s_setprio(1);
#pragma unroll
    for (int m = 0; m < 4; ++m)
#pragma unroll
      for (int n = 0; n < 2; ++n)
#pragma unroll
        for (int kk = 0; kk < 2; ++kk)
          acc[4+m][2+n] = __builtin_amdgcn_mfma_f32_16x16x32_bf16(af[m][kk], bf1[n][kk], acc[4+m][2+n], 0, 0, 0);
    __builtin_amdgcn_s_setprio(0);
    if (t + 1 < nk) {
      if (t + 2 < nk) { asm volatile("s_waitcnt vmcnt(4)" ::: "memory"); }
      else            { asm volatile("s_waitcnt vmcnt(0)" ::: "memory"); }
    }
    BAR();
  }
#undef STAGE_A
#undef STAGE_B
#undef FRAG

  // epilogue — launder pointers so the compiler can't hoist these vmem loads
  // into the counted-vmcnt main loop
  uintptr_t bp = (uintptr_t)bias;  asm volatile("" : "+v"(bp));
  uintptr_t rp = (uintptr_t)res;   asm volatile("" : "+v"(rp));
  const float* biasq = (const float*)bp;
  const float* resq  = (const float*)rp;
  const int er = (l >> 4) << 2;
#pragma unroll
  for (int n = 0; n < 4; ++n) {
    const long col = rB0 + (n >> 1)*128 + (n & 1)*64 + wn*16 + fr;
    const float bv = biasq[col];
#pragma unroll
    for (int m = 0; m < 8; ++m) {
      const long row0 = rA0 + (m >> 2)*128 + (m & 3)*32 + wm*16 + er;
#pragma unroll
      for (int j = 0; j < 4; ++j) {
        const long off = (row0 + j)*(long)N + col;
        const float v = acc[m][n][j] + bv;
        if (MODE == 0)      outB[off] = (bf16_t)v;
        else if (MODE == 1) outB[off] = (bf16_t)fmaxf(v, 0.f);
        else                outF[off] = v + resq[off];
      }
    }
  }
}

// ---------------- attention: one block per (b, head) -----------------------
__global__ __launch_bounds__(256) void attn_k(
    const bf16_t* __restrict__ qb, const bf16_t* __restrict__ kb,
    const bf16_t* __restrict__ vb, bf16_t* __restrict__ ob)
{
  __shared__ __align__(16) char smem[64*128*2*2 + 64*64*4 + 64*4];
  bf16_t* Qc = (bf16_t*)smem;
  bf16_t* Kc = (bf16_t*)(smem + 16384);
  bf16_t* Vc = (bf16_t*)smem;                  // aliases Qc (phase-disjoint)
  float*  E    = (float*)(smem + 32768);
  float*  Rinv = (float*)(smem + 49152);

  const int tid  = threadIdx.x;
  const int head = blockIdx.x & 7, b = blockIdx.x >> 3;
  const long rbase = (long)head*32 + b;

  const int ti = tid >> 2, g = tid & 3;
  const int lr  = tid >> 2;
  const int lp0 = (tid & 3) * 4;

  float eacc[16];
#pragma unroll
  for (int j = 0; j < 16; ++j) eacc[j] = 0.f;

  for (int kc = 0; kc < HID; kc += 128) {
    __syncthreads();
    const bf16_t* qrow = qb + (lr*256 + rbase)*HID + kc;
    const bf16_t* krow = kb + (lr*256 + rbase)*HID + kc;
#pragma unroll
    for (int i = 0; i < 4; ++i) {
      const int p = lp0 + i;
      const int src = (p ^ (lr & 7)) * 8;
      *(uint4*)&Qc[lr*128 + p*8] = *(const uint4*)&qrow[src];
      *(uint4*)&Kc[lr*128 + p*8] = *(const uint4*)&krow[src];
    }
    __syncthreads();
    for (int e8 = 0; e8 < 16; ++e8) {
      const int qp = e8 ^ (ti & 7);
      bf16x8 qv = *(bf16x8*)&Qc[ti*128 + qp*8];
      float qf[8];
#pragma unroll
      for (int u = 0; u < 8; ++u) qf[u] = (float)qv[u];
#pragma unroll
      for (int j = 0; j < 16; ++j) {
        const int s  = j*4 + g;
        const int kp = e8 ^ (s & 7);
        bf16x8 kv = *(bf16x8*)&Kc[s*128 + kp*8];
        float a = eacc[j];
#pragma unroll
        for (int u = 0; u < 8; ++u) a += qf[u] * (float)kv[u];
        eacc[j] = a;
      }
    }
  }
  const float scale = 0.0883883476483184f;     // 1/sqrt(128)
  float mx = -1e30f;
#pragma unroll
  for (int j = 0; j < 16; ++j) { eacc[j] *= scale; mx = fmaxf(mx, eacc[j]); }
  mx = fmaxf(mx, __shfl_xor(mx, 1));
  mx = fmaxf(mx, __shfl_xor(mx, 2));
  float sum = 0.f;
#pragma unroll
  for (int j = 0; j < 16; ++j) {
    const float pj = __expf(eacc[j] - mx);
    E[(j*4 + g)*64 + ti] = pj;
    sum += pj;
  }
  sum += __shfl_xor(sum, 1);
  sum += __shfl_xor(sum, 2);
  if (g == 0) Rinv[ti] = 1.f / sum;
  __syncthreads();

  const int lane = tid & 63, wq_ = tid >> 6;
  const float rv = Rinv[lane];
  const long orow = (long)lane*256 + b*8 + head;
  for (int fc = 0; fc < HID; fc += 128) {
    __syncthreads();
    const bf16_t* vrow = vb + (lr*256 + rbase)*HID + fc;
#pragma unroll
    for (int i = 0; i < 4; ++i) {
      const int p = lp0 + i;
      *(uint4*)&Vc[lr*128 + p*8] = *(const uint4*)&vrow[p*8];
    }
    __syncthreads();
    float vacc[32];
#pragma unroll
    for (int u = 0; u < 32; ++u) vacc[u] = 0.f;
    for (int s = 0; s < 64; ++s) {
      const float pp = E[s*64 + lane];
#pragma unroll
      for (int u = 0; u < 4; ++u) {
        bf16x8 vv = *(bf16x8*)&Vc[s*128 + wq_*32 + u*8];
#pragma unroll
        for (int t8 = 0; t8 < 8; ++t8) vacc[u*8 + t8] += pp * (float)vv[t8];
      }
    }
#pragma unroll
    for (int u = 0; u < 4; ++u) {
      bf16x8 ov;
#pragma unroll
      for (int t8 = 0; t8 < 8; ++t8) ov[t8] = (bf16_t)(vacc[u*8 + t8] * rv);
      *(bf16x8*)&ob[orow*HID + fc + wq_*32 + u*8] = ov;
    }
  }
}

// ---------------- global layer-norm: 2-stage reduce + normalize ------------
__global__ __launch_bounds__(256) void reduce1(const float* __restrict__ t,
                                               float* __restrict__ part, long n4)
{
  float s = 0.f, s2 = 0.f;
  for (long i = (long)blockIdx.x*blockDim.x + threadIdx.x; i < n4;
       i += (long)gridDim.x*blockDim.x) {
    float4 v = ((const float4*)t)[i];
    s  += v.x + v.y + v.z + v.w;
    s2 += v.x*v.x + v.y*v.y + v.z*v.z + v.w*v.w;
  }
  __shared__ float sh[256], sh2[256];
  const int tid = threadIdx.x;
  sh[tid] = s; sh2[tid] = s2; __syncthreads();
  for (int o = 128; o > 0; o >>= 1) {
    if (tid < o) { sh[tid] += sh[tid+o]; sh2[tid] += sh2[tid+o]; }
    __syncthreads();
  }
  if (tid == 0) { part[blockIdx.x] = sh[0]; part[2048 + blockIdx.x] = sh2[0]; }
}

__global__ __launch_bounds__(256) void reduce2(const float* __restrict__ part,
                                               float* __restrict__ stats)
{
  __shared__ double sh[256], sh2[256];
  const int tid = threadIdx.x;
  double s = 0.0, s2 = 0.0;
  for (int i = tid; i < 2048; i += 256) { s += part[i]; s2 += part[2048 + i]; }
  sh[tid] = s; sh2[tid] = s2; __syncthreads();
  for (int o = 128; o > 0; o >>= 1) {
    if (tid < o) { sh[tid] += sh[tid+o]; sh2[tid] += sh2[tid+o]; }
    __syncthreads();
  }
  if (tid == 0) {
    const double n = (double)NTOT;
    const double mean = sh[0] / n;
    const double var  = sh2[0] / n - mean*mean;
    stats[0] = (float)mean;
    stats[1] = (float)(1.0 / sqrt(var + 1e-5));
  }
}

__global__ __launch_bounds__(256) void ln_norm(const float* __restrict__ t,
    const float* __restrict__ stats, float* __restrict__ outF,
    bf16_t* __restrict__ outB, long n4)
{
  const float mean = stats[0], rstd = stats[1];
  for (long i = (long)blockIdx.x*blockDim.x + threadIdx.x; i < n4;
       i += (long)gridDim.x*blockDim.x) {
    float4 v = ((const float4*)t)[i];
    float4 o = {(v.x-mean)*rstd, (v.y-mean)*rstd, (v.z-mean)*rstd, (v.w-mean)*rstd};
    ((float4*)outF)[i] = o;
    bf16x4 ob = {(bf16_t)o.x, (bf16_t)o.y, (bf16_t)o.z, (bf16_t)o.w};
    ((bf16x4*)outB)[i] = ob;
  }
}

// ---------------------------------------------------------------------------
extern "C" void kernel_launch(void* const* d_in, const int* in_sizes, int n_in,
                              void* d_out, int out_size, void* d_ws, size_t ws_size,
                              hipStream_t stream)
{
  const int*   x    = (const int*)  d_in[0];
  const float* emb  = (const float*)d_in[1];
  const float* pos  = (const float*)d_in[2];
  const float* wq_a = (const float*)d_in[3];
  const float* bq_a = (const float*)d_in[4];
  const float* wk_a = (const float*)d_in[5];
  const float* bk_a = (const float*)d_in[6];
  const float* wv_a = (const float*)d_in[7];
  const float* bv_a = (const float*)d_in[8];
  const float* wo_a = (const float*)d_in[9];
  const float* bo_a = (const float*)d_in[10];
  const float* w1_a = (const float*)d_in[11];
  const float* b1_a = (const float*)d_in[12];
  const float* w2_a = (const float*)d_in[13];
  const float* b2_a = (const float*)d_in[14];

  char* p = (char*)d_ws;
  auto take = [&](size_t n) { char* r = p; p += (n + 255) & ~(size_t)255; return r; };
  float*  h    = (float*) take(NTOT*4);
  bf16_t* hb   = (bf16_t*)take(NTOT*2);
  bf16_t* U    = (bf16_t*)take((size_t)NROW*FFD*2);
  bf16_t* qb   = U;
  bf16_t* kb   = U + NTOT;
  bf16_t* vbuf = U + 2*NTOT;
  bf16_t* attb = U + 3*NTOT;
  bf16_t* ff1  = U;
  bf16_t* wT   = (bf16_t*)take((size_t)FFD*HID*2);
  float*  part = (float*) take(4096*4);
  float*  stats= (float*) take(256);

  const long n4 = NTOT / 4;
  const int gH  = (NROW/256)*(HID/256);                 // 256 blocks
  const int gF  = (NROW/256)*(FFD/256);                 // 1024 blocks

  embed_k<<<NROW, 256, 0, stream>>>(x, emb, pos, h, hb);

  for (int i = 0; i < 6; ++i) {
    const float* Wq = wq_a + (size_t)i*HID*HID;  const float* Bq = bq_a + (size_t)i*HID;
    const float* Wk = wk_a + (size_t)i*HID*HID;  const float* Bk = bk_a + (size_t)i*HID;
    const float* Wv = wv_a + (size_t)i*HID*HID;  const float* Bv = bv_a + (size_t)i*HID;
    const float* Wo = wo_a + (size_t)i*HID*HID;  const float* Bo = bo_a + (size_t)i*HID;
    const float* W1 = w1_a + (size_t)i*HID*FFD;  const float* B1 = b1_a + (size_t)i*FFD;
    const float* W2 = w2_a + (size_t)i*FFD*HID;  const float* B2 = b2_a + (size_t)i*HID;

    wcvt<<<(HID/32)*(HID/32), 256, 0, stream>>>(Wq, wT, HID, HID);
    gemm256<0><<<gH, 512, 0, stream>>>(hb, wT, Bq, nullptr, nullptr, qb, NROW, HID, HID);
    wcvt<<<(HID/32)*(HID/32), 256, 0, stream>>>(Wk, wT, HID, HID);
    gemm256<0><<<gH, 512, 0, stream>>>(hb, wT, Bk, nullptr, nullptr, kb, NROW, HID, HID);
    wcvt<<<(HID/32)*(HID/32), 256, 0, stream>>>(Wv, wT, HID, HID);
    gemm256<0><<<gH, 512, 0, stream>>>(hb, wT, Bv, nullptr, nullptr, vbuf, NROW, HID, HID);

    attn_k<<<256, 256, 0, stream>>>(qb, kb, vbuf, attb);

    wcvt<<<(HID/32)*(HID/32), 256, 0, stream>>>(Wo, wT, HID, HID);
    gemm256<2><<<gH, 512, 0, stream>>>(attb, wT, Bo, h, h, nullptr, NROW, HID, HID);

    reduce1<<<2048, 256, 0, stream>>>(h, part, n4);
    reduce2<<<1, 256, 0, stream>>>(part, stats);
    ln_norm<<<2048, 256, 0, stream>>>(h, stats, h, hb, n4);

    wcvt<<<(FFD/32)*(HID/32), 256, 0, stream>>>(W1, wT, HID, FFD);
    gemm256<1><<<gF, 512, 0, stream>>>(hb, wT, B1, nullptr, nullptr, ff1, NROW, FFD, HID);
    wcvt<<<(HID/32)*(FFD/32), 256, 0, stream>>>(W2, wT, FFD, HID);
    gemm256<2><<<gH, 512, 0, stream>>>(ff1, wT, B2, h, h, nullptr, NROW, HID, FFD);

    reduce1<<<2048, 256, 0, stream>>>(h, part, n4);
    reduce2<<<1, 256, 0, stream>>>(part, stats);
    ln_norm<<<2048, 256, 0, stream>>>(h, stats, (i == 5) ? (float*)d_out : h, hb, n4);
  }
}